// Round 6
// baseline (35.710 us; speedup 1.0000x reference)
//
#include <hip/hip_runtime.h>

// Problem constants (from reference): x[64][32768][15] f32, hidden sizes 4/4/4.
#define SEQ   64
#define BATCH 32768
#define FEAT  15
#define SLAB  (BATCH * FEAT)   // dwords per timestep slab of x

#define LOG2E 1.4426950408889634f

typedef float v2f __attribute__((ext_vector_type(2)));

__device__ __forceinline__ float fast_rcp(float x) { return __builtin_amdgcn_rcpf(x); }
__device__ __forceinline__ float ex2(float x)      { return __builtin_amdgcn_exp2f(x); }
// sig2(t) = 1/(1+2^t).  sigmoid(x) = sig2(-L*x); tanh(x) = 1 - 2*sig2(2L*x).
__device__ __forceinline__ float sig2(float t)     { return fast_rcp(1.0f + ex2(t)); }

// Quad (4-lane) DPP move: CTRL = j*0x55 broadcasts lane j of each quad;
// 0xB1 = quad_perm [1,0,3,2] (xor1), 0x4E = [2,3,0,1] (xor2).
template <int CTRL>
__device__ __forceinline__ float qmov(float v) {
    return __int_as_float(
        __builtin_amdgcn_mov_dpp(__float_as_int(v), CTRL, 0xf, 0xf, false));
}

// packed f32 fma: a*b + c with ffp-contract -> v_pk_fma_f32 on gfx950
__device__ __forceinline__ v2f fma2(v2f a, v2f b, v2f c) { return a * b + c; }

struct Fq { float a, b, c, d; };   // one step's 4 own-features (static regs)

__global__ __launch_bounds__(256, 2) void lstm_fused(
    const float* __restrict__ x,
    const float* __restrict__ w1,  const float* __restrict__ b1,
    const float* __restrict__ w2,  const float* __restrict__ b2,
    const float* __restrict__ wih, const float* __restrict__ whh,
    const float* __restrict__ bih, const float* __restrict__ bhh,
    const float* __restrict__ w3,  const float* __restrict__ b3,
    float* __restrict__ out)
{
    const int tid = threadIdx.x;
    const int w   = tid >> 6;          // wave in block
    const int l   = tid & 63;          // lane
    const int u   = l & 3;             // lane-in-quad
    const int e   = l >> 2;            // element within the wave's 16
    const int elem = blockIdx.x * 64 + w * 16 + e;   // this quad's batch element

    // lane u owns features [qoff, qoff+4): {0,4,8,11}; feature 11 is loaded by
    // both lane2 (k=3) and lane3 (k=0) - lane3's copy is weight-zeroed.
    const int qoff = (u == 3) ? 11 : 4 * u;
    const float* xp = x + (size_t)elem * FEAT + qoff;

    // ---- weights ----
    // fc1: per-lane partial dot for ALL 4 units over own 4 features.
    v2f W1a[4], W1b[4], SE[4];
#pragma unroll
    for (int j = 0; j < 4; ++j) {
        const float* r = w1 + j * FEAT + qoff;
        W1a[j] = v2f{(u == 3) ? 0.0f : r[0], r[1]};   // dedup feature 11
        W1b[j] = v2f{r[2], r[3]};
        SE[j]  = v2f{(u == 0) ? b1[j] : 0.0f, 0.0f};  // bias seeded on lane0 only
    }
    // fc2 (unit u), pre-scaled by -log2e for sig2
    float W2s[4];
#pragma unroll
    for (int j = 0; j < 4; ++j) W2s[j] = -LOG2E * w2[u * 4 + j];
    const float B2v = -LOG2E * b2[u];
    // gates (torch order i,f,g,o): lane u owns all 4 gates of unit u.
    // i,f,o scaled -log2e (sigmoid); g scaled +2log2e (tanh).
    v2f WIp[4][2], WHp[4][2], BIg[4];
#pragma unroll
    for (int g = 0; g < 4; ++g) {
        const float sg = (g == 2) ? (2.0f * LOG2E) : -LOG2E;
        const int row = (g * 4 + u) * 4;
        WIp[g][0] = v2f{sg * wih[row + 0], sg * wih[row + 1]};
        WIp[g][1] = v2f{sg * wih[row + 2], sg * wih[row + 3]};
        WHp[g][0] = v2f{sg * whh[row + 0], sg * whh[row + 1]};
        WHp[g][1] = v2f{sg * whh[row + 2], sg * whh[row + 3]};
        BIg[g]    = v2f{sg * (bih[g * 4 + u] + bhh[g * 4 + u]), 0.0f};
    }
    const float W3v = -LOG2E * w3[u];
    const float B3v = -LOG2E * b3[0];

    float h = 0.0f, c = 0.0f;

    auto step = [&](Fq q) {
        // fc1: own-feature partials for all 4 units (packed), then hadd
        const v2f f01 = v2f{q.a, q.b}, f23 = v2f{q.c, q.d};
        float P[4];
#pragma unroll
        for (int j = 0; j < 4; ++j) {
            const v2f p2 = fma2(W1a[j], f01, fma2(W1b[j], f23, SE[j]));
            P[j] = p2.x + p2.y;
        }
        // quad butterfly all-reduce: every lane gets all 4 full fc1 dots
#pragma unroll
        for (int j = 0; j < 4; ++j) {
            P[j] += qmov<0xB1>(P[j]);
            P[j] += qmov<0x4E>(P[j]);
            P[j] = fmaxf(P[j], 0.0f);          // relu
        }
        // fc2 (unit u) + sigmoid
        const float a2n = fmaf(W2s[0], P[0], fmaf(W2s[1], P[1],
                          fmaf(W2s[2], P[2], fmaf(W2s[3], P[3], B2v))));
        const float h2 = sig2(a2n);
        // broadcast h2 across the quad as two packed pairs
        const v2f q01 = v2f{qmov<0x00>(h2), qmov<0x55>(h2)};
        const v2f q23 = v2f{qmov<0xAA>(h2), qmov<0xFF>(h2)};
        // input-to-gate projection (packed over the j index)
        v2f A[4];
#pragma unroll
        for (int g = 0; g < 4; ++g)
            A[g] = fma2(WIp[g][0], q01, fma2(WIp[g][1], q23, BIg[g]));
        // recurrent projection
        const v2f h01 = v2f{qmov<0x00>(h), qmov<0x55>(h)};
        const v2f h23 = v2f{qmov<0xAA>(h), qmov<0xFF>(h)};
#pragma unroll
        for (int g = 0; g < 4; ++g)
            A[g] = fma2(WHp[g][0], h01, fma2(WHp[g][1], h23, A[g]));
        // activations (inputs pre-scaled)
        const float ig = sig2(A[0].x + A[0].y);
        const float fg = sig2(A[1].x + A[1].y);
        const float gt = fmaf(-2.0f, sig2(A[2].x + A[2].y), 1.0f);
        const float og = sig2(A[3].x + A[3].y);
        c = fmaf(fg, c, ig * gt);
        const float tc = fmaf(-2.0f, sig2(c * (2.0f * LOG2E)), 1.0f);
        h = og * tc;
    };

    auto ld4 = [](const float* p) {
        Fq r; r.a = p[0]; r.b = p[1]; r.c = p[2]; r.d = p[3]; return r;
    };

    // ---- triple-buffered ring: 8 phases x 8 steps, 2 phases in flight ----
    Fq QA[8], QB[8], QC[8];
    auto prefetch8 = [&](Fq* Q, int phase) {
        const float* base = xp + (size_t)(phase * 8) * SLAB;
#pragma unroll
        for (int j = 0; j < 8; ++j) Q[j] = ld4(base + (size_t)j * SLAB);
    };
    auto compute8 = [&](Fq* Q) {
#pragma unroll
        for (int j = 0; j < 8; ++j) step(Q[j]);
    };

    prefetch8(QA, 0);
    prefetch8(QB, 1);
    prefetch8(QC, 2);
    __builtin_amdgcn_sched_barrier(0);
    // phases 0..7; after computing phase i (freeing its buffer), immediately
    // issue phase i+3 into it, so 2 full phases stay in flight at all times.
#pragma unroll 1
    for (int i = 0; i < 2; ++i) {
        compute8(QA);
        __builtin_amdgcn_sched_barrier(0);
        prefetch8(QA, 3 * i + 3);
        __builtin_amdgcn_sched_barrier(0);
        compute8(QB);
        __builtin_amdgcn_sched_barrier(0);
        prefetch8(QB, 3 * i + 4);
        __builtin_amdgcn_sched_barrier(0);
        compute8(QC);
        __builtin_amdgcn_sched_barrier(0);
        if (3 * i + 5 < 8) {
            prefetch8(QC, 3 * i + 5);
            __builtin_amdgcn_sched_barrier(0);
        }
    }
    compute8(QA);   // phase 6
    compute8(QB);   // phase 7

    // ---- head: out[e] = sigmoid(w3·h + b3), quad reduction (scaled) ----
    float p = W3v * h;
    p += qmov<0xB1>(p);
    p += qmov<0x4E>(p);
    if (u == 0) out[elem] = sig2(p + B3v);
}

extern "C" void kernel_launch(void* const* d_in, const int* in_sizes, int n_in,
                              void* d_out, int out_size, void* d_ws, size_t ws_size,
                              hipStream_t stream) {
    (void)in_sizes; (void)n_in; (void)d_ws; (void)ws_size; (void)out_size;
    const float* x   = (const float*)d_in[0];
    const float* w1  = (const float*)d_in[1];
    const float* b1  = (const float*)d_in[2];
    const float* w2  = (const float*)d_in[3];
    const float* b2  = (const float*)d_in[4];
    const float* wih = (const float*)d_in[5];
    const float* whh = (const float*)d_in[6];
    const float* bih = (const float*)d_in[7];
    const float* bhh = (const float*)d_in[8];
    const float* w3  = (const float*)d_in[9];
    const float* b3  = (const float*)d_in[10];
    float* out = (float*)d_out;

    // 512 blocks x 256 threads = 2048 waves; one quad (4 lanes) per batch element.
    lstm_fused<<<dim3(512), dim3(256), 0, stream>>>(
        x, w1, b1, w2, b2, wih, whh, bih, bhh, w3, b3, out);
}

// Round 7
// 33.263 us; speedup vs baseline: 1.0736x; 1.0736x over previous
//
#include <hip/hip_runtime.h>

// Problem constants (from reference): x[64][32768][15] f32, hidden sizes 4/4/4.
#define SEQ   64
#define BATCH 32768
#define FEAT  15
#define SLAB  (BATCH * FEAT)   // dwords per timestep slab of x

#define LOG2E 1.4426950408889634f

typedef float v2f __attribute__((ext_vector_type(2)));

__device__ __forceinline__ float fast_rcp(float x) { return __builtin_amdgcn_rcpf(x); }
__device__ __forceinline__ float ex2(float x)      { return __builtin_amdgcn_exp2f(x); }
// sig2(t) = 1/(1+2^t).  sigmoid(x) = sig2(-L*x); tanh(x) = 1 - 2*sig2(2L*x).
__device__ __forceinline__ float sig2(float t)     { return fast_rcp(1.0f + ex2(t)); }

// Quad (4-lane) DPP move: CTRL = j*0x55 broadcasts lane j of each quad;
// 0xB1 = quad_perm [1,0,3,2] (xor1), 0x4E = [2,3,0,1] (xor2).
template <int CTRL>
__device__ __forceinline__ float qmov(float v) {
    return __int_as_float(
        __builtin_amdgcn_mov_dpp(__float_as_int(v), CTRL, 0xf, 0xf, false));
}

// packed f32 fma: a*b + c with ffp-contract -> v_pk_fma_f32 on gfx950
__device__ __forceinline__ v2f fma2(v2f a, v2f b, v2f c) { return a * b + c; }

struct Fq { float a, b, c, d; };   // one step's 4 own-features (static regs)

__global__ __launch_bounds__(256, 2) void lstm_fused(
    const float* __restrict__ x,
    const float* __restrict__ w1,  const float* __restrict__ b1,
    const float* __restrict__ w2,  const float* __restrict__ b2,
    const float* __restrict__ wih, const float* __restrict__ whh,
    const float* __restrict__ bih, const float* __restrict__ bhh,
    const float* __restrict__ w3,  const float* __restrict__ b3,
    float* __restrict__ out)
{
    const int tid = threadIdx.x;
    const int w   = tid >> 6;          // wave in block
    const int l   = tid & 63;          // lane
    const int u   = l & 3;             // lane-in-quad
    const int e   = l >> 2;            // element within the wave's 16
    const int elem = blockIdx.x * 64 + w * 16 + e;   // this quad's batch element

    // lane u owns features [qoff, qoff+4): {0,4,8,11}; feature 11 is loaded by
    // both lane2 (k=3) and lane3 (k=0) - lane3's copy is weight-zeroed.
    const int qoff = (u == 3) ? 11 : 4 * u;
    const float* xp = x + (size_t)elem * FEAT + qoff;

    // ---- weights ----
    // fc1: per-lane partial dot for ALL 4 units over own 4 features.
    v2f W1a[4], W1b[4], SE[4];
#pragma unroll
    for (int j = 0; j < 4; ++j) {
        const float* r = w1 + j * FEAT + qoff;
        W1a[j] = v2f{(u == 3) ? 0.0f : r[0], r[1]};   // dedup feature 11
        W1b[j] = v2f{r[2], r[3]};
        SE[j]  = v2f{(u == 0) ? b1[j] : 0.0f, 0.0f};  // bias seeded on lane0 only
    }
    // fc2 (unit u) as a packed dot, pre-scaled by -log2e for sig2
    const v2f W2p0 = v2f{-LOG2E * w2[u * 4 + 0], -LOG2E * w2[u * 4 + 1]};
    const v2f W2p1 = v2f{-LOG2E * w2[u * 4 + 2], -LOG2E * w2[u * 4 + 3]};
    const v2f B2p  = v2f{-LOG2E * b2[u], 0.0f};
    // gates (torch order i,f,g,o): lane u owns all 4 gates of unit u.
    // i,f,o scaled -log2e (sigmoid); g scaled +2log2e (tanh).
    v2f WIp[4][2], WHp[4][2], BIg[4];
#pragma unroll
    for (int g = 0; g < 4; ++g) {
        const float sg = (g == 2) ? (2.0f * LOG2E) : -LOG2E;
        const int row = (g * 4 + u) * 4;
        WIp[g][0] = v2f{sg * wih[row + 0], sg * wih[row + 1]};
        WIp[g][1] = v2f{sg * wih[row + 2], sg * wih[row + 3]};
        WHp[g][0] = v2f{sg * whh[row + 0], sg * whh[row + 1]};
        WHp[g][1] = v2f{sg * whh[row + 2], sg * whh[row + 3]};
        BIg[g]    = v2f{sg * (bih[g * 4 + u] + bhh[g * 4 + u]), 0.0f};
    }
    const float W3v = -LOG2E * w3[u];
    const float B3v = -LOG2E * b3[0];

    float h = 0.0f, c = 0.0f;

    // Front-end MLP: x-fragment -> h2 (unit u). Independent of (h,c), so it
    // is software-pipelined one step ahead of the recurrence.
    auto mlp = [&](Fq q) -> float {
        const v2f f01 = v2f{q.a, q.b}, f23 = v2f{q.c, q.d};
        float P[4];
#pragma unroll
        for (int j = 0; j < 4; ++j) {
            const v2f p2 = fma2(W1a[j], f01, fma2(W1b[j], f23, SE[j]));
            P[j] = p2.x + p2.y;
        }
#pragma unroll
        for (int j = 0; j < 4; ++j) {
            P[j] += qmov<0xB1>(P[j]);
            P[j] += qmov<0x4E>(P[j]);
            P[j] = fmaxf(P[j], 0.0f);          // relu
        }
        const v2f p01 = v2f{P[0], P[1]}, p23 = v2f{P[2], P[3]};
        const v2f acc = fma2(W2p0, p01, fma2(W2p1, p23, B2p));
        return sig2(acc.x + acc.y);
    };

    // Recurrence step: gates from (h2_cur, h) -> activations -> c,h update.
    auto recur = [&](float h2c) {
        const v2f q01 = v2f{qmov<0x00>(h2c), qmov<0x55>(h2c)};
        const v2f q23 = v2f{qmov<0xAA>(h2c), qmov<0xFF>(h2c)};
        v2f A[4];
#pragma unroll
        for (int g = 0; g < 4; ++g)
            A[g] = fma2(WIp[g][0], q01, fma2(WIp[g][1], q23, BIg[g]));
        const v2f h01 = v2f{qmov<0x00>(h), qmov<0x55>(h)};
        const v2f h23 = v2f{qmov<0xAA>(h), qmov<0xFF>(h)};
#pragma unroll
        for (int g = 0; g < 4; ++g)
            A[g] = fma2(WHp[g][0], h01, fma2(WHp[g][1], h23, A[g]));
        const float ig = sig2(A[0].x + A[0].y);
        const float fg = sig2(A[1].x + A[1].y);
        const float gt = fmaf(-2.0f, sig2(A[2].x + A[2].y), 1.0f);
        const float og = sig2(A[3].x + A[3].y);
        c = fmaf(fg, c, ig * gt);
        const float tc = fmaf(-2.0f, sig2(c * (2.0f * LOG2E)), 1.0f);
        h = og * tc;
    };

    auto ld4 = [](const float* p) {
        Fq r; r.a = p[0]; r.b = p[1]; r.c = p[2]; r.d = p[3]; return r;
    };

    Fq QA[8], QB[8];
    auto prefetch8 = [&](Fq* Q, int phase) {
        const float* base = xp + (size_t)(phase * 8) * SLAB;
#pragma unroll
        for (int j = 0; j < 8; ++j) Q[j] = ld4(base + (size_t)j * SLAB);
    };

    // ---- pipeline: double-buffered loads; h2 computed one step ahead ----
    prefetch8(QA, 0);                      // slabs 0..7
    float h2c = mlp(QA[0]);                // h2 for step 0 (stalls once, ok)
#pragma unroll 1
    for (int i = 0; i < 3; ++i) {
        prefetch8(QB, 2 * i + 1);
        __builtin_amdgcn_sched_barrier(0); // loads may not sink
#pragma unroll
        for (int j = 0; j < 8; ++j) {      // steps 16i .. 16i+7
            const float h2n = mlp((j < 7) ? QA[j + 1] : QB[0]);
            recur(h2c);
            h2c = h2n;
        }
        prefetch8(QA, 2 * i + 2);
        __builtin_amdgcn_sched_barrier(0);
#pragma unroll
        for (int j = 0; j < 8; ++j) {      // steps 16i+8 .. 16i+15
            const float h2n = mlp((j < 7) ? QB[j + 1] : QA[0]);
            recur(h2c);
            h2c = h2n;
        }
    }
    prefetch8(QB, 7);
    __builtin_amdgcn_sched_barrier(0);
#pragma unroll
    for (int j = 0; j < 8; ++j) {          // steps 48..55
        const float h2n = mlp((j < 7) ? QA[j + 1] : QB[0]);
        recur(h2c);
        h2c = h2n;
    }
#pragma unroll
    for (int j = 0; j < 8; ++j) {          // steps 56..63
        float h2n = 0.0f;
        if (j < 7) h2n = mlp(QB[j + 1]);
        recur(h2c);
        h2c = h2n;
    }

    // ---- head: out[e] = sigmoid(w3·h + b3), quad reduction (scaled) ----
    float p = W3v * h;
    p += qmov<0xB1>(p);
    p += qmov<0x4E>(p);
    if (u == 0) out[elem] = sig2(p + B3v);
}

extern "C" void kernel_launch(void* const* d_in, const int* in_sizes, int n_in,
                              void* d_out, int out_size, void* d_ws, size_t ws_size,
                              hipStream_t stream) {
    (void)in_sizes; (void)n_in; (void)d_ws; (void)ws_size; (void)out_size;
    const float* x   = (const float*)d_in[0];
    const float* w1  = (const float*)d_in[1];
    const float* b1  = (const float*)d_in[2];
    const float* w2  = (const float*)d_in[3];
    const float* b2  = (const float*)d_in[4];
    const float* wih = (const float*)d_in[5];
    const float* whh = (const float*)d_in[6];
    const float* bih = (const float*)d_in[7];
    const float* bhh = (const float*)d_in[8];
    const float* w3  = (const float*)d_in[9];
    const float* b3  = (const float*)d_in[10];
    float* out = (float*)d_out;

    // 512 blocks x 256 threads = 2048 waves; one quad (4 lanes) per batch element.
    lstm_fused<<<dim3(512), dim3(256), 0, stream>>>(
        x, w1, b1, w2, b2, wih, whh, bih, bhh, w3, b3, out);
}

// Round 8
// 30.307 us; speedup vs baseline: 1.1783x; 1.0975x over previous
//
#include <hip/hip_runtime.h>

// Problem constants: x[64][32768][15] f32, hidden sizes 4/4/4.
#define SEQ   64
#define BATCH 32768
#define FEAT  15
#define SLABBYTES (BATCH * FEAT * 4)   // 1,966,080 bytes per timestep slab

#define LOG2E 1.4426950408889634f

typedef float v2f __attribute__((ext_vector_type(2)));
typedef float v4f __attribute__((ext_vector_type(4)));

__device__ __forceinline__ float fast_rcp(float x) { return __builtin_amdgcn_rcpf(x); }
__device__ __forceinline__ float ex2(float x)      { return __builtin_amdgcn_exp2f(x); }
// sig2(t) = 1/(1+2^t).  sigmoid(x) = sig2(-L*x); tanh(x) = 1 - 2*sig2(2L*x).
__device__ __forceinline__ float sig2(float t)     { return fast_rcp(1.0f + ex2(t)); }

// Quad (4-lane) DPP move: CTRL = j*0x55 broadcasts lane j of each quad.
template <int CTRL>
__device__ __forceinline__ float qmov(float v) {
    return __int_as_float(
        __builtin_amdgcn_mov_dpp(__float_as_int(v), CTRL, 0xf, 0xf, false));
}

// packed f32 fma -> v_pk_fma_f32
__device__ __forceinline__ v2f fma2(v2f a, v2f b, v2f c) { return a * b + c; }

template <int N>
__device__ __forceinline__ void waitv() {
    asm volatile("s_waitcnt vmcnt(%0)" :: "n"(N) : "memory");
}
template <int N>
__device__ __forceinline__ void waitlg() {
    asm volatile("s_waitcnt lgkmcnt(%0)" :: "n"(N) : "memory");
}

typedef const __attribute__((address_space(1))) void gas_t;
typedef __attribute__((address_space(3))) void las_t;

__global__ __launch_bounds__(256, 2) void lstm_fused(
    const float* __restrict__ x,
    const float* __restrict__ w1,  const float* __restrict__ b1,
    const float* __restrict__ w2,  const float* __restrict__ b2,
    const float* __restrict__ wih, const float* __restrict__ whh,
    const float* __restrict__ bih, const float* __restrict__ bhh,
    const float* __restrict__ w3,  const float* __restrict__ b3,
    float* __restrict__ out)
{
    // 4 waves/block; per wave: 8-buffer ring, 1 KiB per buffer (16 rows x 64 B).
    __shared__ __align__(16) float lds[4][8][256];   // 32 KiB/block

    const int tid = threadIdx.x;
    const int w   = tid >> 6;          // wave in block
    const int l   = tid & 63;          // lane
    const int u   = l & 3;             // lane-in-quad (owns hidden unit u)
    const int e   = l >> 2;            // element (=row) within the wave's 16
    const int ebase = blockIdx.x * 64 + w * 16;
    const int elem  = ebase + e;

    // ---- DMA source pre-swizzle (dest is linear: lane k -> bytes [16k,16k+16)) ----
    // dest lane k covers row r=k>>2, slot q=k&3. Layout: slot q of row r holds
    // part p = (q - perm(r)) & 3, perm(r) = (r + (r>>2)) & 3  (2-way banks max).
    // Parts: p0=bytes 0..15, p1=16..31, p2=32..47, p3=44..59 (word 11 dup; never
    // crosses the slab end, so no OOB).
    const int perm_e = (e + (e >> 2)) & 3;
    const int p      = (u - perm_e) & 3;
    const int inrow  = (p < 3) ? p * 16 : 44;
    uint32_t off = (uint32_t)(ebase + e) * 60u + (uint32_t)inrow;   // slab-0 source byte

    auto gload = [&](int b, uint32_t o) {
        __builtin_amdgcn_global_load_lds(
            (gas_t*)((const char*)x + o),
            (las_t*)&lds[w][b][0], 16, 0, 0);
    };

    // ---- reader-side slot bases (float index within a buffer) for parts 0..3 ----
    int sb[4];
#pragma unroll
    for (int pp = 0; pp < 4; ++pp) sb[pp] = (4 * e + ((pp + perm_e) & 3)) * 4;

    auto ldrow = [&](int b, v4f& F0, v4f& F1, v4f& F2, v4f& F3) {
        const float* B = &lds[w][b][0];
        F0 = *(const v4f*)(B + sb[0]);   // words 0..3
        F1 = *(const v4f*)(B + sb[1]);   // words 4..7
        F2 = *(const v4f*)(B + sb[2]);   // words 8..11
        F3 = *(const v4f*)(B + sb[3]);   // words 11..14 (x = dup of 11)
    };

    // ---- weights (same math as R5; sig/tanh inputs pre-scaled by +-log2e) ----
    float W1[FEAT];
#pragma unroll
    for (int f = 0; f < FEAT; ++f) W1[f] = w1[u * FEAT + f];
    const float B1v = b1[u];
    float W2s[4];
#pragma unroll
    for (int j = 0; j < 4; ++j) W2s[j] = -LOG2E * w2[u * 4 + j];
    const float B2v = -LOG2E * b2[u];
    v2f WIp[4][2], WHp[4][2], BIg[4];
#pragma unroll
    for (int g = 0; g < 4; ++g) {
        const float sg = (g == 2) ? (2.0f * LOG2E) : -LOG2E;   // torch order i,f,g,o
        const int row = (g * 4 + u) * 4;
        WIp[g][0] = v2f{sg * wih[row + 0], sg * wih[row + 1]};
        WIp[g][1] = v2f{sg * wih[row + 2], sg * wih[row + 3]};
        WHp[g][0] = v2f{sg * whh[row + 0], sg * whh[row + 1]};
        WHp[g][1] = v2f{sg * whh[row + 2], sg * whh[row + 3]};
        BIg[g]    = v2f{sg * (bih[g * 4 + u] + bhh[g * 4 + u]), 0.0f};
    }
    const float W3v = -LOG2E * w3[u];
    const float B3v = -LOG2E * b3[0];

    float h = 0.0f, c = 0.0f;

    auto step = [&](v4f F0, v4f F1, v4f F2, v4f F3) {
        // fc1 (unit u): all 15 features broadcast from LDS; 3 split chains
        float a0 = B1v, a1 = 0.0f, a2 = 0.0f;
        a0 = fmaf(W1[0], F0.x, a0);  a0 = fmaf(W1[1], F0.y, a0);
        a0 = fmaf(W1[2], F0.z, a0);  a0 = fmaf(W1[3], F0.w, a0);
        a0 = fmaf(W1[4], F1.x, a0);
        a1 = fmaf(W1[5], F1.y, a1);  a1 = fmaf(W1[6], F1.z, a1);
        a1 = fmaf(W1[7], F1.w, a1);  a1 = fmaf(W1[8], F2.x, a1);
        a1 = fmaf(W1[9], F2.y, a1);
        a2 = fmaf(W1[10], F2.z, a2); a2 = fmaf(W1[11], F2.w, a2);
        a2 = fmaf(W1[12], F3.y, a2); a2 = fmaf(W1[13], F3.z, a2);
        a2 = fmaf(W1[14], F3.w, a2);
        const float h1 = fmaxf(a0 + (a1 + a2), 0.0f);
        // fc2 (unit u) + sigmoid
        const float t0 = qmov<0x00>(h1), t1 = qmov<0x55>(h1);
        const float t2 = qmov<0xAA>(h1), t3 = qmov<0xFF>(h1);
        const float a2n = fmaf(W2s[0], t0, fmaf(W2s[1], t1,
                          fmaf(W2s[2], t2, fmaf(W2s[3], t3, B2v))));
        const float h2 = sig2(a2n);
        // gates (packed over j)
        const v2f q01 = v2f{qmov<0x00>(h2), qmov<0x55>(h2)};
        const v2f q23 = v2f{qmov<0xAA>(h2), qmov<0xFF>(h2)};
        v2f A[4];
#pragma unroll
        for (int g = 0; g < 4; ++g)
            A[g] = fma2(WIp[g][0], q01, fma2(WIp[g][1], q23, BIg[g]));
        const v2f h01 = v2f{qmov<0x00>(h), qmov<0x55>(h)};
        const v2f h23 = v2f{qmov<0xAA>(h), qmov<0xFF>(h)};
#pragma unroll
        for (int g = 0; g < 4; ++g)
            A[g] = fma2(WHp[g][0], h01, fma2(WHp[g][1], h23, A[g]));
        const float ig = sig2(A[0].x + A[0].y);
        const float fg = sig2(A[1].x + A[1].y);
        const float gt = fmaf(-2.0f, sig2(A[2].x + A[2].y), 1.0f);
        const float og = sig2(A[3].x + A[3].y);
        c = fmaf(fg, c, ig * gt);
        const float tc = fmaf(-2.0f, sig2(c * (2.0f * LOG2E)), 1.0f);
        h = og * tc;
    };

    // ---- prologue: fill the ring (slabs 0..7), read row 0 ----
#pragma unroll
    for (int b = 0; b < 8; ++b) { gload(b, off); off += SLABBYTES; }
    waitv<7>();                                  // slab 0 landed
    __builtin_amdgcn_sched_barrier(0);
    v4f F0, F1, F2, F3;
    ldrow(0, F0, F1, F2, F3);

    // ---- main loop: steps 0..55; steady state = 7-8 DMAs always in flight ----
#pragma unroll 1
    for (int ph = 0; ph < 7; ++ph) {
#pragma unroll
        for (int j = 0; j < 8; ++j) {            // step s = 8*ph + j
            waitv<6>();                          // slab s+1 landed
            __builtin_amdgcn_sched_barrier(0);
            v4f G0, G1, G2, G3;
            ldrow((j + 1) & 7, G0, G1, G2, G3);  // row s+1
            waitlg<4>();                         // row-s reads retired -> buf s&7 free
            __builtin_amdgcn_sched_barrier(0);
            gload(j, off);  off += SLABBYTES;    // slab s+8 -> buffer s&7
            step(F0, F1, F2, F3);                // compute step s
            F0 = G0; F1 = G1; F2 = G2; F3 = G3;
        }
    }
    // ---- epilogue: steps 56..63, ring drains ----
#define EPI(JJ, NN)                                                   \
    {   waitv<NN>();                                                  \
        __builtin_amdgcn_sched_barrier(0);                            \
        v4f G0, G1, G2, G3;                                           \
        ldrow(((JJ) + 1) & 7, G0, G1, G2, G3);                        \
        step(F0, F1, F2, F3);                                         \
        F0 = G0; F1 = G1; F2 = G2; F3 = G3; }
    EPI(0, 6) EPI(1, 5) EPI(2, 4) EPI(3, 3) EPI(4, 2) EPI(5, 1) EPI(6, 0)
#undef EPI
    step(F0, F1, F2, F3);                        // step 63

    // ---- head: out[e] = sigmoid(w3·h + b3), quad reduction (scaled) ----
    float pr = W3v * h;
    pr += qmov<0xB1>(pr);
    pr += qmov<0x4E>(pr);
    if (u == 0) out[elem] = sig2(pr + B3v);
}

extern "C" void kernel_launch(void* const* d_in, const int* in_sizes, int n_in,
                              void* d_out, int out_size, void* d_ws, size_t ws_size,
                              hipStream_t stream) {
    (void)in_sizes; (void)n_in; (void)d_ws; (void)ws_size; (void)out_size;
    const float* x   = (const float*)d_in[0];
    const float* w1  = (const float*)d_in[1];
    const float* b1  = (const float*)d_in[2];
    const float* w2  = (const float*)d_in[3];
    const float* b2  = (const float*)d_in[4];
    const float* wih = (const float*)d_in[5];
    const float* whh = (const float*)d_in[6];
    const float* bih = (const float*)d_in[7];
    const float* bhh = (const float*)d_in[8];
    const float* w3  = (const float*)d_in[9];
    const float* b3  = (const float*)d_in[10];
    float* out = (float*)d_out;

    // 512 blocks x 256 threads = 2048 waves; one quad (4 lanes) per batch element.
    lstm_fused<<<dim3(512), dim3(256), 0, stream>>>(
        x, w1, b1, w2, b2, wih, whh, bih, bhh, w3, b3, out);
}